// Round 10
// baseline (450.629 us; speedup 1.0000x reference)
//
#include <hip/hip_runtime.h>
#include <hip/hip_bf16.h>

#define NT 8192
#define NS 8192
#define FD 128
#define PD 128
#define KTOP 2457                      /* max(1, int(8192*0.3)) */
#define TAUINV 14.285714285714286f     /* 1/0.07 */
#define HSIZE 65536
#define HMASK 65535
#define NBIN 512
#define CAND_MAX 2048
#define NMC 4096                       /* matched rows = N_S/2 by construction */

typedef __attribute__((ext_vector_type(8))) short s16x8;
typedef __attribute__((ext_vector_type(4))) float f32x4;

__device__ __forceinline__ float bf2f(unsigned short u) {
  return __uint_as_float(((unsigned)u) << 16);
}
__device__ __forceinline__ unsigned short f2bf(float x) {   // RNE
  unsigned u = __float_as_uint(x);
  return (unsigned short)((u + 0x7FFF + ((u >> 16) & 1)) >> 16);
}

// ---------------------------------------------------------------------------
__global__ __launch_bounds__(256) void init_ws(float* stats, int* hkey,
                                               int* nmatch, float* dsum,
                                               unsigned* dcnt)
{
  int i = blockIdx.x * 256 + threadIdx.x;
  if (i < 512) stats[i] = 0.f;
  if (i < HSIZE) hkey[i] = -1;
  if (i == 0) { *nmatch = 0; *dsum = 0.f; *dcnt = 0u; }
}

// ---------------------------------------------------------------------------
// Projection MLP (pre-BN) for BOTH nets: blockIdx.y = 0 teacher / 1 student.
// ---------------------------------------------------------------------------
__global__ __launch_bounds__(256) void proj_mlp2(
    const float* __restrict__ Xt, const float* __restrict__ Xs2,
    const float* __restrict__ tW1, const float* __restrict__ tB1,
    const float* __restrict__ tW2, const float* __restrict__ tB2,
    const float* __restrict__ sW1, const float* __restrict__ sB1,
    const float* __restrict__ sW2, const float* __restrict__ sB2,
    float* __restrict__ Ht, float* __restrict__ Hs2, float* __restrict__ stats)
{
  int f = blockIdx.y;
  const float* X  = f ? Xs2 : Xt;
  const float* W1 = f ? sW1 : tW1;
  const float* B1 = f ? sB1 : tB1;
  const float* W2 = f ? sW2 : tW2;
  const float* B2 = f ? sB2 : tB2;
  float* H        = f ? Hs2 : Ht;
  float* colsum   = stats + f * 256;
  float* colsq    = colsum + 128;

  __shared__ __align__(16) float Xs[32][128];
  __shared__ __align__(16) float H1s[32][128];
  __shared__ float cs[128], cq[128];
  int tid = threadIdx.x;
  int r0 = blockIdx.x * 32;
  for (int i = tid; i < 32 * 32; i += 256) {
    int r = i >> 5, q = i & 31;
    ((float4*)Xs[r])[q] = ((const float4*)(X + (size_t)(r0 + r) * FD))[q];
  }
  if (tid < 128) { cs[tid] = 0.f; cq[tid] = 0.f; }
  __syncthreads();

  int c  = (tid & 63) * 2;
  int rg = (tid >> 6) * 8;
  float a0[8], a1[8];
  #pragma unroll
  for (int r = 0; r < 8; ++r) { a0[r] = 0.f; a1[r] = 0.f; }
  for (int k = 0; k < FD; ++k) {
    float2 w = *(const float2*)(W1 + k * FD + c);
    #pragma unroll
    for (int r = 0; r < 8; ++r) {
      float x = Xs[rg + r][k];
      a0[r] = fmaf(x, w.x, a0[r]);
      a1[r] = fmaf(x, w.y, a1[r]);
    }
  }
  float2 b = *(const float2*)(B1 + c);
  #pragma unroll
  for (int r = 0; r < 8; ++r) {
    H1s[rg + r][c]     = fmaxf(a0[r] + b.x, 0.f);
    H1s[rg + r][c + 1] = fmaxf(a1[r] + b.y, 0.f);
  }
  __syncthreads();

  #pragma unroll
  for (int r = 0; r < 8; ++r) { a0[r] = 0.f; a1[r] = 0.f; }
  for (int k = 0; k < FD; ++k) {
    float2 w = *(const float2*)(W2 + k * PD + c);
    #pragma unroll
    for (int r = 0; r < 8; ++r) {
      float x = H1s[rg + r][k];
      a0[r] = fmaf(x, w.x, a0[r]);
      a1[r] = fmaf(x, w.y, a1[r]);
    }
  }
  b = *(const float2*)(B2 + c);
  float s0 = 0.f, s1 = 0.f, q0 = 0.f, q1 = 0.f;
  #pragma unroll
  for (int r = 0; r < 8; ++r) {
    float h0 = a0[r] + b.x, h1 = a1[r] + b.y;
    *(float2*)(H + (size_t)(r0 + rg + r) * PD + c) = make_float2(h0, h1);
    s0 += h0; s1 += h1; q0 += h0 * h0; q1 += h1 * h1;
  }
  atomicAdd(&cs[c], s0);     atomicAdd(&cs[c + 1], s1);
  atomicAdd(&cq[c], q0);     atomicAdd(&cq[c + 1], q1);
  __syncthreads();
  if (tid < 128) { atomicAdd(&colsum[tid], cs[tid]); atomicAdd(&colsq[tid], cq[tid]); }
}

// ---------------------------------------------------------------------------
// BN + row-L2-normalize -> split bf16, both nets (blockIdx.y flag).
// ---------------------------------------------------------------------------
__global__ __launch_bounds__(256) void bn_l2_2(
    const float* __restrict__ Ht, const float* __restrict__ Hs2,
    const float* __restrict__ stats,
    const float* __restrict__ t_gamma, const float* __restrict__ t_beta,
    const float* __restrict__ s_gamma, const float* __restrict__ s_beta,
    unsigned short* __restrict__ Th, unsigned short* __restrict__ Tl,
    unsigned short* __restrict__ ShC, unsigned short* __restrict__ SlC,
    const int* __restrict__ minv)
{
  int f = blockIdx.y;
  const float* H = f ? Hs2 : Ht;
  const float* colsum = stats + f * 256;
  const float* colsq  = colsum + 128;
  const float* gamma  = f ? s_gamma : t_gamma;
  const float* beta   = f ? s_beta : t_beta;
  unsigned short* Oh  = f ? ShC : Th;
  unsigned short* Ol  = f ? SlC : Tl;
  const float invN = 1.f / (float)NT;

  __shared__ float part[2][2];
  int half = threadIdx.x >> 7;
  int c    = threadIdx.x & 127;
  int wih  = (threadIdx.x >> 6) & 1;
  int row  = blockIdx.x * 2 + half;
  float mu  = colsum[c] * invN;
  float var = colsq[c] * invN - mu * mu;
  float inv = rsqrtf(var + 1e-5f);
  float y = (H[(size_t)row * PD + c] - mu) * inv * gamma[c] + beta[c];
  float sq = y * y;
  #pragma unroll
  for (int off = 32; off >= 1; off >>= 1) sq += __shfl_xor(sq, off, 64);
  if ((threadIdx.x & 63) == 0) part[half][wih] = sq;
  __syncthreads();
  float norm = sqrtf(part[half][0] + part[half][1]);
  float r = y / norm;
  int orow = f ? minv[row] : row;
  if (orow >= 0) {
    unsigned ub = __float_as_uint(r);
    float fhi = __uint_as_float(ub & 0xFFFF0000u);
    float lo  = r - fhi;
    Oh[(size_t)orow * PD + c] = (unsigned short)(ub >> 16);
    Ol[(size_t)orow * PD + c] = (unsigned short)(__float_as_uint(lo) >> 16);
  }
}

// ---------------------------------------------------------------------------
// Coordinate hash (teacher keys unique).  Lookup also compacts matched rows.
// ---------------------------------------------------------------------------
__device__ __forceinline__ int coord_key(int4 c) {
  return ((c.x * 64 + c.y) * 128 + c.z) * 128 + c.w;
}

__global__ __launch_bounds__(256) void hash_insert(
    const int* __restrict__ coords, int* __restrict__ hkey, int* __restrict__ hval)
{
  int t = blockIdx.x * 256 + threadIdx.x;
  if (t >= NT) return;
  int key = coord_key(((const int4*)coords)[t]);
  unsigned slot = (((unsigned)key * 2654435761u) >> 16) & HMASK;
  while (true) {
    int old = atomicCAS(&hkey[slot], -1, key);
    if (old == -1) { hval[slot] = t; break; }
    slot = (slot + 1) & HMASK;
  }
}

__global__ __launch_bounds__(256) void hash_lookup(
    const int* __restrict__ coords, const int* __restrict__ hkey,
    const int* __restrict__ hval, int* __restrict__ minv,
    int* __restrict__ mt, int* __restrict__ nmatch)
{
  int s = blockIdx.x * 256 + threadIdx.x;
  if (s >= NS) return;
  int key = coord_key(((const int4*)coords)[s]);
  unsigned slot = (((unsigned)key * 2654435761u) >> 16) & HMASK;
  int res = -1;
  while (true) {
    int k = hkey[slot];
    if (k == key) { res = hval[slot]; break; }
    if (k == -1) break;
    slot = (slot + 1) & HMASK;
  }
  int cslot = -1;
  if (res >= 0) { cslot = atomicAdd(nmatch, 1); mt[cslot] = res; }
  minv[s] = cslot;
}

// ---------------------------------------------------------------------------
// Split-bf16 MFMA GEMM -> bf16 P.  (unchanged, proven r6-r9)
// ---------------------------------------------------------------------------
__device__ __forceinline__ void gload16(const void* g, void* l) {
  __builtin_amdgcn_global_load_lds(
      (const __attribute__((address_space(1))) unsigned int*)g,
      (__attribute__((address_space(3))) unsigned int*)l, 16, 0, 0);
}

__global__ __launch_bounds__(256) void gemm_bf16x2(
    const unsigned short* __restrict__ ShC, const unsigned short* __restrict__ SlC,
    const unsigned short* __restrict__ Th, const unsigned short* __restrict__ Tl,
    unsigned short* __restrict__ Pb, const int* __restrict__ nmatch)
{
  int ay = blockIdx.x, bx = blockIdx.y;        // x = A tile (fast dim)
  if (ay * 128 >= *nmatch) return;

  __shared__ unsigned short lds[32768];        // Bh 32KB | Bl 32KB
  int tid = threadIdx.x, lane = tid & 63, wid = tid >> 6;

  const unsigned short* gB[2] = { Th + (size_t)bx * 128 * FD,
                                  Tl + (size_t)bx * 128 * FD };
  #pragma unroll
  for (int comp = 0; comp < 2; ++comp) {
    const char* g = (const char*)gB[comp];
    char* lb = (char*)lds + comp * 32768;
    #pragma unroll
    for (int it = 0; it < 8; ++it) {
      int chunk0 = it * 256 + wid * 64;
      int d = (chunk0 + lane) * 16;
      int src = d ^ (((d >> 8) & 7) << 4);
      gload16(g + src, lb + chunk0 * 16);
    }
  }

  int wr = wid >> 1, wc = wid & 1;             // 2x2 waves of 64x64
  const unsigned short* gA_h = ShC + (size_t)(ay * 128) * FD;
  const unsigned short* gA_l = SlC + (size_t)(ay * 128) * FD;
  int rA[4];
  #pragma unroll
  for (int m = 0; m < 4; ++m) rA[m] = wr * 64 + m * 16 + (lane & 15);
  int cA0 = (lane >> 4) * 8;

  s16x8 nah[4], nal[4];                        // kk=0 prefetch
  #pragma unroll
  for (int m = 0; m < 4; ++m) {
    nah[m] = *(const s16x8*)(gA_h + (size_t)rA[m] * FD + cA0);
    nal[m] = *(const s16x8*)(gA_l + (size_t)rA[m] * FD + cA0);
  }
  __syncthreads();

  f32x4 acc[4][4] = {};
  #pragma unroll
  for (int kk = 0; kk < 4; ++kk) {
    s16x8 ah[4], al[4];
    #pragma unroll
    for (int m = 0; m < 4; ++m) { ah[m] = nah[m]; al[m] = nal[m]; }
    if (kk < 3) {
      int cA = (kk + 1) * 32 + cA0;
      #pragma unroll
      for (int m = 0; m < 4; ++m) {
        nah[m] = *(const s16x8*)(gA_h + (size_t)rA[m] * FD + cA);
        nal[m] = *(const s16x8*)(gA_l + (size_t)rA[m] * FD + cA);
      }
    }
    int cB = kk * 32 + cA0;
    s16x8 bh[4], bl[4];
    #pragma unroll
    for (int n = 0; n < 4; ++n) {
      int r = wc * 64 + n * 16 + (lane & 15);
      int byt = r * 256 + ((cB * 2) ^ ((r & 7) << 4));
      bh[n] = *(const s16x8*)((const char*)lds + byt);
      bl[n] = *(const s16x8*)((const char*)lds + 32768 + byt);
    }
    #pragma unroll
    for (int m = 0; m < 4; ++m)
      #pragma unroll
      for (int n = 0; n < 4; ++n) {
        acc[m][n] = __builtin_amdgcn_mfma_f32_16x16x32_bf16(ah[m], bh[n], acc[m][n], 0, 0, 0);
        acc[m][n] = __builtin_amdgcn_mfma_f32_16x16x32_bf16(ah[m], bl[n], acc[m][n], 0, 0, 0);
        acc[m][n] = __builtin_amdgcn_mfma_f32_16x16x32_bf16(al[m], bh[n], acc[m][n], 0, 0, 0);
      }
  }

  // C/D layout: col = lane&15, row = (lane>>4)*4 + reg
  #pragma unroll
  for (int m = 0; m < 4; ++m)
    #pragma unroll
    for (int n = 0; n < 4; ++n) {
      int pc = bx * 128 + wc * 64 + n * 16 + (lane & 15);
      int pr0 = ay * 128 + wr * 64 + m * 16 + (lane >> 4) * 4;
      #pragma unroll
      for (int reg = 0; reg < 4; ++reg)
        Pb[(size_t)(pr0 + reg) * NT + pc] = f2bf(acc[m][n][reg] * TAUINV);
    }
}

// ---------------------------------------------------------------------------
// Exact top-k + logsumexp. Row staged in LDS (16 KB bf16) -- NO per-thread
// arrays (r7/r9's 32-elem register rows were silently spilled to scratch:
// VGPR_Count 28-36 < 32x4B).  Adaptive-range 512-bin count histogram
// (value-uniform over [row_min,row_max] -> near-zero atomic aliasing, unlike
// r8's bit-pattern bins), shuffle-based suffix scan (2 barriers), candidate
// rank (exact ties), exp only over survivors.  Fused pos + final mean.
// ---------------------------------------------------------------------------
__global__ __launch_bounds__(256) void select_lse(
    const unsigned short* __restrict__ Pb,
    const unsigned short* __restrict__ ShC, const unsigned short* __restrict__ SlC,
    const unsigned short* __restrict__ Th, const unsigned short* __restrict__ Tl,
    const int* __restrict__ mt, const int* __restrict__ nmatch,
    float* __restrict__ dsum, unsigned* __restrict__ dcnt,
    float* __restrict__ out)
{
  __shared__ __align__(16) unsigned short row[NT];   // 16 KB
  __shared__ unsigned hist[NBIN];                    // 2 KB
  __shared__ float cand[CAND_MAX];                   // 8 KB
  __shared__ float redMx[4], redMn[4], redF[4];
  __shared__ int redI[4];
  __shared__ unsigned wsum[4];
  __shared__ float sh_pos, sh_theta;
  __shared__ int sh_B, sh_j;
  __shared__ unsigned sh_cc;

  int tid = threadIdx.x, lane = tid & 63, wid = tid >> 6;
  int slot = blockIdx.x;
  int nm = *nmatch;
  bool active = slot < nm;

  if (active) {
    const unsigned short* p = Pb + (size_t)slot * NT;

    // ---- wave 0: exact f32 positive dot (128 elems, 2/lane) ----
    if (wid == 0) {
      int t = mt[slot];
      int k0 = lane * 2;
      float a0 = bf2f(ShC[(size_t)slot * FD + k0])     + bf2f(SlC[(size_t)slot * FD + k0]);
      float a1 = bf2f(ShC[(size_t)slot * FD + k0 + 1]) + bf2f(SlC[(size_t)slot * FD + k0 + 1]);
      float b0 = bf2f(Th[(size_t)t * FD + k0])         + bf2f(Tl[(size_t)t * FD + k0]);
      float b1 = bf2f(Th[(size_t)t * FD + k0 + 1])     + bf2f(Tl[(size_t)t * FD + k0 + 1]);
      float sum = fmaf(a1, b1, a0 * b0);
      #pragma unroll
      for (int off = 32; off >= 1; off >>= 1) sum += __shfl_xor(sum, off, 64);
      if (lane == 0) sh_pos = sum * TAUINV;
    }

    // ---- load pass: global -> LDS row, track min/max ----
    float mx = -1e30f, mn = 1e30f;
    #pragma unroll
    for (int q = 0; q < 4; ++q) {
      s16x8 v = ((const s16x8*)p)[tid + 256 * q];
      ((s16x8*)row)[tid + 256 * q] = v;
      #pragma unroll
      for (int j = 0; j < 8; ++j) {
        float f = bf2f((unsigned short)v[j]);
        mx = fmaxf(mx, f);
        mn = fminf(mn, f);
      }
    }
    #pragma unroll
    for (int off = 32; off >= 1; off >>= 1) {
      mx = fmaxf(mx, __shfl_xor(mx, off, 64));
      mn = fminf(mn, __shfl_xor(mn, off, 64));
    }
    if (lane == 0) { redMx[wid] = mx; redMn[wid] = mn; }
    hist[tid] = 0; hist[tid + 256] = 0;
    if (tid == 0) sh_cc = 0;
    __syncthreads();                                           // B1

    float M  = fmaxf(fmaxf(redMx[0], redMx[1]), fmaxf(redMx[2], redMx[3]));
    float mn4 = fminf(fminf(redMn[0], redMn[1]), fminf(redMn[2], redMn[3]));
    float lo = mn4;
    float scale = (float)NBIN / fmaxf(M - mn4, 1e-9f);

    // ---- histogram pass (LDS row, adaptive bins) ----
    for (int i = tid; i < NT; i += 256) {
      float v = bf2f(row[i]);
      int bb = (int)((v - lo) * scale);
      bb = bb < 0 ? 0 : (bb > NBIN - 1 ? NBIN - 1 : bb);
      atomicAdd(&hist[bb], 1u);
    }
    __syncthreads();                                           // B2

    // ---- shuffle suffix-scan: thread t owns bins 2t, 2t+1 ----
    unsigned c0 = hist[2 * tid], c1 = hist[2 * tid + 1];
    unsigned s = c0 + c1;
    #pragma unroll
    for (int off = 1; off <= 32; off <<= 1) {
      unsigned t2 = __shfl_down(s, off, 64);
      if (lane + off < 64) s += t2;
    }
    if (lane == 0) wsum[wid] = s;     // s at lane 0 = wave's 128-bin total
    __syncthreads();                                           // B3
    unsigned add = 0;
    for (int w2 = wid + 1; w2 < 4; ++w2) add += wsum[w2];
    unsigned S0 = s + add;            // suffix sum from bin 2t
    unsigned S1 = S0 - c0;            // suffix sum from bin 2t+1
    if (c0 && S0 >= (unsigned)KTOP && S1 < (unsigned)KTOP) {
      sh_B = 2 * tid;  sh_j = KTOP - (int)S1;
    }
    unsigned S2 = S1 - c1;
    if (c1 && S1 >= (unsigned)KTOP && S2 < (unsigned)KTOP) {
      sh_B = 2 * tid + 1;  sh_j = KTOP - (int)S2;
    }
    __syncthreads();                                           // B4
    int B = sh_B;

    // ---- collect threshold-bin candidates ----
    for (int i = tid; i < NT; i += 256) {
      float v = bf2f(row[i]);
      int bb = (int)((v - lo) * scale);
      bb = bb < 0 ? 0 : (bb > NBIN - 1 ? NBIN - 1 : bb);
      if (bb == B) {
        unsigned idx = atomicAdd(&sh_cc, 1u);
        if (idx < CAND_MAX) cand[idx] = v;
      }
    }
    __syncthreads();                                           // B5
    int c = (int)sh_cc; if (c > CAND_MAX) c = CAND_MAX;
    int jrem = sh_j;   if (jrem > c) jrem = c;     // overflow/degenerate guard

    // ---- exact jrem-th largest among candidates (tie-exact) ----
    float thl = -1e30f;
    for (int i = tid; i < c; i += 256) {
      float v = cand[i];
      int gt = 0, eq = 0;
      for (int m = 0; m < c; ++m) {
        float u = cand[m];
        gt += (u > v) ? 1 : 0;
        eq += (u == v) ? 1 : 0;
      }
      if (gt < jrem && jrem <= gt + eq) thl = v;
    }
    #pragma unroll
    for (int off = 32; off >= 1; off >>= 1) thl = fmaxf(thl, __shfl_xor(thl, off, 64));
    if (lane == 0) redF[wid] = thl;
    __syncthreads();                                           // B6
    if (tid == 0) sh_theta = fmaxf(fmaxf(redF[0], redF[1]), fmaxf(redF[2], redF[3]));
    __syncthreads();                                           // B7

    float theta = sh_theta;
    float pos = sh_pos;
    float Mp = fmaxf(M, pos);

    // ---- exp-sum over strict top, tie copies via count ----
    float esum = 0.f; int g = 0;
    for (int i = tid; i < NT; i += 256) {
      float v = bf2f(row[i]);
      if (v > theta) { esum += __expf(v - Mp); g++; }
    }
    #pragma unroll
    for (int off = 32; off >= 1; off >>= 1) {
      esum += __shfl_xor(esum, off, 64);
      g    += __shfl_xor(g, off, 64);
    }
    if (lane == 0) { redF[wid] = esum; redI[wid] = g; }
    __syncthreads();                                           // B8
    if (tid == 0) {
      float E = redF[0] + redF[1] + redF[2] + redF[3];
      int   G = redI[0] + redI[1] + redI[2] + redI[3];
      float S = E + (float)(KTOP - G) * __expf(theta - Mp) + __expf(pos - Mp);
      atomicAdd(dsum, logf(S) + Mp - pos);
    }
  }

  // ---- last-block finalize: mean over matched rows ----
  __threadfence();
  if (tid == 0) {
    unsigned old = atomicAdd(dcnt, 1u);
    if (old == (unsigned)gridDim.x - 1u) {
      __threadfence();
      float S = *(volatile float*)dsum;
      out[0] = S / fmaxf((float)nm, 1.f);
    }
  }
}

// ---------------------------------------------------------------------------
extern "C" void kernel_launch(void* const* d_in, const int* in_sizes, int n_in,
                              void* d_out, int out_size, void* d_ws, size_t ws_size,
                              hipStream_t stream)
{
  const float* t_feat  = (const float*)d_in[0];
  const float* s_feat  = (const float*)d_in[1];
  const float* t_w1    = (const float*)d_in[2];
  const float* t_b1    = (const float*)d_in[3];
  const float* t_w2    = (const float*)d_in[4];
  const float* t_b2    = (const float*)d_in[5];
  const float* t_gamma = (const float*)d_in[6];
  const float* t_beta  = (const float*)d_in[7];
  const float* s_w1    = (const float*)d_in[8];
  const float* s_b1    = (const float*)d_in[9];
  const float* s_w2    = (const float*)d_in[10];
  const float* s_b2    = (const float*)d_in[11];
  const float* s_gamma = (const float*)d_in[12];
  const float* s_beta  = (const float*)d_in[13];
  const int*   t_coord = (const int*)d_in[14];
  const int*   s_coord = (const int*)d_in[15];

  // ws layout (bytes), ws_size = 256 MiB:
  //  0x000000 Th 2MB | 0x200000 Tl 2MB | 0x400000 ShC 2MB | 0x600000 SlC 2MB
  //  0x800000 stats 2KB | 0x800800 hkey 256KB | 0x840800 hval 256KB
  //  0x880800 nmatch | 0x880900 mt 32KB | 0x888900 minv 32KB
  //  0x890900 dsum 4B | 0x890908 dcnt 4B
  //  0x8B0000 Ht 4MB, Hs 4MB (dead after bn) -- Pb bf16 (64MB) aliases here
  char* w = (char*)d_ws;
  unsigned short* Th  = (unsigned short*)(w + 0x000000);
  unsigned short* Tl  = (unsigned short*)(w + 0x200000);
  unsigned short* ShC = (unsigned short*)(w + 0x400000);
  unsigned short* SlC = (unsigned short*)(w + 0x600000);
  float* stats  = (float*)(w + 0x800000);
  int*   hkey   = (int*)(w + 0x800800);
  int*   hval   = (int*)(w + 0x840800);
  int*   nmatch = (int*)(w + 0x880800);
  int*   mt     = (int*)(w + 0x880900);
  int*   minv   = (int*)(w + 0x888900);
  float* dsum   = (float*)(w + 0x890900);
  unsigned* dcnt = (unsigned*)(w + 0x890908);
  float* Ht     = (float*)(w + 0x8B0000);
  float* Hs     = (float*)(w + 0xCB0000);
  unsigned short* Pb = (unsigned short*)(w + 0x8B0000);  // aliases Ht/Hs

  init_ws<<<HSIZE / 256, 256, 0, stream>>>(stats, hkey, nmatch, dsum, dcnt);
  hash_insert<<<NT / 256, 256, 0, stream>>>(t_coord, hkey, hval);
  hash_lookup<<<NS / 256, 256, 0, stream>>>(s_coord, hkey, hval, minv, mt, nmatch);

  {
    dim3 g(NT / 32, 2);
    proj_mlp2<<<g, 256, 0, stream>>>(t_feat, s_feat,
                                     t_w1, t_b1, t_w2, t_b2,
                                     s_w1, s_b1, s_w2, s_b2,
                                     Ht, Hs, stats);
  }
  {
    dim3 g(NT / 2, 2);
    bn_l2_2<<<g, 256, 0, stream>>>(Ht, Hs, stats, t_gamma, t_beta,
                                   s_gamma, s_beta, Th, Tl, ShC, SlC, minv);
  }
  {
    dim3 g(NMC / 128, NT / 128);             // x = A tiles (fast), y = B tiles
    gemm_bf16x2<<<g, 256, 0, stream>>>(ShC, SlC, Th, Tl, Pb, nmatch);
  }
  select_lse<<<NMC, 256, 0, stream>>>(Pb, ShC, SlC, Th, Tl, mt, nmatch,
                                      dsum, dcnt, (float*)d_out);
}

// Round 11
// 237.848 us; speedup vs baseline: 1.8946x; 1.8946x over previous
//
#include <hip/hip_runtime.h>
#include <hip/hip_bf16.h>

#define NT 8192
#define NS 8192
#define FD 128
#define PD 128
#define KTOP 2457                      /* max(1, int(8192*0.3)) */
#define TAUINV 14.285714285714286f     /* 1/0.07 */
#define HSIZE 65536
#define HMASK 65535
#define NBIN 512
#define CAND_MAX 2048
#define NMC 4096                       /* matched rows = N_S/2 by construction */

typedef __attribute__((ext_vector_type(8))) short s16x8;
typedef __attribute__((ext_vector_type(4))) float f32x4;

__device__ __forceinline__ float bf2f(unsigned short u) {
  return __uint_as_float(((unsigned)u) << 16);
}
__device__ __forceinline__ unsigned short f2bf(float x) {   // RNE
  unsigned u = __float_as_uint(x);
  return (unsigned short)((u + 0x7FFF + ((u >> 16) & 1)) >> 16);
}

// ---------------------------------------------------------------------------
__global__ __launch_bounds__(256) void init_ws(float* stats, int* hkey,
                                               int* nmatch)
{
  int i = blockIdx.x * 256 + threadIdx.x;
  if (i < 512) stats[i] = 0.f;
  if (i < HSIZE) hkey[i] = -1;
  if (i == 0) *nmatch = 0;
}

// ---------------------------------------------------------------------------
// Projection MLP (pre-BN) for BOTH nets: blockIdx.y = 0 teacher / 1 student.
// ---------------------------------------------------------------------------
__global__ __launch_bounds__(256) void proj_mlp2(
    const float* __restrict__ Xt, const float* __restrict__ Xs2,
    const float* __restrict__ tW1, const float* __restrict__ tB1,
    const float* __restrict__ tW2, const float* __restrict__ tB2,
    const float* __restrict__ sW1, const float* __restrict__ sB1,
    const float* __restrict__ sW2, const float* __restrict__ sB2,
    float* __restrict__ Ht, float* __restrict__ Hs2, float* __restrict__ stats)
{
  int f = blockIdx.y;
  const float* X  = f ? Xs2 : Xt;
  const float* W1 = f ? sW1 : tW1;
  const float* B1 = f ? sB1 : tB1;
  const float* W2 = f ? sW2 : tW2;
  const float* B2 = f ? sB2 : tB2;
  float* H        = f ? Hs2 : Ht;
  float* colsum   = stats + f * 256;
  float* colsq    = colsum + 128;

  __shared__ __align__(16) float Xs[32][128];
  __shared__ __align__(16) float H1s[32][128];
  __shared__ float cs[128], cq[128];
  int tid = threadIdx.x;
  int r0 = blockIdx.x * 32;
  for (int i = tid; i < 32 * 32; i += 256) {
    int r = i >> 5, q = i & 31;
    ((float4*)Xs[r])[q] = ((const float4*)(X + (size_t)(r0 + r) * FD))[q];
  }
  if (tid < 128) { cs[tid] = 0.f; cq[tid] = 0.f; }
  __syncthreads();

  int c  = (tid & 63) * 2;
  int rg = (tid >> 6) * 8;
  float a0[8], a1[8];
  #pragma unroll
  for (int r = 0; r < 8; ++r) { a0[r] = 0.f; a1[r] = 0.f; }
  for (int k = 0; k < FD; ++k) {
    float2 w = *(const float2*)(W1 + k * FD + c);
    #pragma unroll
    for (int r = 0; r < 8; ++r) {
      float x = Xs[rg + r][k];
      a0[r] = fmaf(x, w.x, a0[r]);
      a1[r] = fmaf(x, w.y, a1[r]);
    }
  }
  float2 b = *(const float2*)(B1 + c);
  #pragma unroll
  for (int r = 0; r < 8; ++r) {
    H1s[rg + r][c]     = fmaxf(a0[r] + b.x, 0.f);
    H1s[rg + r][c + 1] = fmaxf(a1[r] + b.y, 0.f);
  }
  __syncthreads();

  #pragma unroll
  for (int r = 0; r < 8; ++r) { a0[r] = 0.f; a1[r] = 0.f; }
  for (int k = 0; k < FD; ++k) {
    float2 w = *(const float2*)(W2 + k * PD + c);
    #pragma unroll
    for (int r = 0; r < 8; ++r) {
      float x = H1s[rg + r][k];
      a0[r] = fmaf(x, w.x, a0[r]);
      a1[r] = fmaf(x, w.y, a1[r]);
    }
  }
  b = *(const float2*)(B2 + c);
  float s0 = 0.f, s1 = 0.f, q0 = 0.f, q1 = 0.f;
  #pragma unroll
  for (int r = 0; r < 8; ++r) {
    float h0 = a0[r] + b.x, h1 = a1[r] + b.y;
    *(float2*)(H + (size_t)(r0 + rg + r) * PD + c) = make_float2(h0, h1);
    s0 += h0; s1 += h1; q0 += h0 * h0; q1 += h1 * h1;
  }
  atomicAdd(&cs[c], s0);     atomicAdd(&cs[c + 1], s1);
  atomicAdd(&cq[c], q0);     atomicAdd(&cq[c + 1], q1);
  __syncthreads();
  if (tid < 128) { atomicAdd(&colsum[tid], cs[tid]); atomicAdd(&colsq[tid], cq[tid]); }
}

// ---------------------------------------------------------------------------
// BN + row-L2-normalize -> split bf16, both nets (blockIdx.y flag).
// ---------------------------------------------------------------------------
__global__ __launch_bounds__(256) void bn_l2_2(
    const float* __restrict__ Ht, const float* __restrict__ Hs2,
    const float* __restrict__ stats,
    const float* __restrict__ t_gamma, const float* __restrict__ t_beta,
    const float* __restrict__ s_gamma, const float* __restrict__ s_beta,
    unsigned short* __restrict__ Th, unsigned short* __restrict__ Tl,
    unsigned short* __restrict__ ShC, unsigned short* __restrict__ SlC,
    const int* __restrict__ minv)
{
  int f = blockIdx.y;
  const float* H = f ? Hs2 : Ht;
  const float* colsum = stats + f * 256;
  const float* colsq  = colsum + 128;
  const float* gamma  = f ? s_gamma : t_gamma;
  const float* beta   = f ? s_beta : t_beta;
  unsigned short* Oh  = f ? ShC : Th;
  unsigned short* Ol  = f ? SlC : Tl;
  const float invN = 1.f / (float)NT;

  __shared__ float part[2][2];
  int half = threadIdx.x >> 7;
  int c    = threadIdx.x & 127;
  int wih  = (threadIdx.x >> 6) & 1;
  int row  = blockIdx.x * 2 + half;
  float mu  = colsum[c] * invN;
  float var = colsq[c] * invN - mu * mu;
  float inv = rsqrtf(var + 1e-5f);
  float y = (H[(size_t)row * PD + c] - mu) * inv * gamma[c] + beta[c];
  float sq = y * y;
  #pragma unroll
  for (int off = 32; off >= 1; off >>= 1) sq += __shfl_xor(sq, off, 64);
  if ((threadIdx.x & 63) == 0) part[half][wih] = sq;
  __syncthreads();
  float norm = sqrtf(part[half][0] + part[half][1]);
  float r = y / norm;
  int orow = f ? minv[row] : row;
  if (orow >= 0) {
    unsigned ub = __float_as_uint(r);
    float fhi = __uint_as_float(ub & 0xFFFF0000u);
    float lo  = r - fhi;
    Oh[(size_t)orow * PD + c] = (unsigned short)(ub >> 16);
    Ol[(size_t)orow * PD + c] = (unsigned short)(__float_as_uint(lo) >> 16);
  }
}

// ---------------------------------------------------------------------------
// Coordinate hash (teacher keys unique).  Lookup also compacts matched rows.
// ---------------------------------------------------------------------------
__device__ __forceinline__ int coord_key(int4 c) {
  return ((c.x * 64 + c.y) * 128 + c.z) * 128 + c.w;
}

__global__ __launch_bounds__(256) void hash_insert(
    const int* __restrict__ coords, int* __restrict__ hkey, int* __restrict__ hval)
{
  int t = blockIdx.x * 256 + threadIdx.x;
  if (t >= NT) return;
  int key = coord_key(((const int4*)coords)[t]);
  unsigned slot = (((unsigned)key * 2654435761u) >> 16) & HMASK;
  while (true) {
    int old = atomicCAS(&hkey[slot], -1, key);
    if (old == -1) { hval[slot] = t; break; }
    slot = (slot + 1) & HMASK;
  }
}

__global__ __launch_bounds__(256) void hash_lookup(
    const int* __restrict__ coords, const int* __restrict__ hkey,
    const int* __restrict__ hval, int* __restrict__ minv,
    int* __restrict__ mt, int* __restrict__ nmatch)
{
  int s = blockIdx.x * 256 + threadIdx.x;
  if (s >= NS) return;
  int key = coord_key(((const int4*)coords)[s]);
  unsigned slot = (((unsigned)key * 2654435761u) >> 16) & HMASK;
  int res = -1;
  while (true) {
    int k = hkey[slot];
    if (k == key) { res = hval[slot]; break; }
    if (k == -1) break;
    slot = (slot + 1) & HMASK;
  }
  int cslot = -1;
  if (res >= 0) { cslot = atomicAdd(nmatch, 1); mt[cslot] = res; }
  minv[s] = cslot;
}

// ---------------------------------------------------------------------------
// Split-bf16 MFMA GEMM -> bf16 P.  (unchanged, proven r6-r10)
// ---------------------------------------------------------------------------
__device__ __forceinline__ void gload16(const void* g, void* l) {
  __builtin_amdgcn_global_load_lds(
      (const __attribute__((address_space(1))) unsigned int*)g,
      (__attribute__((address_space(3))) unsigned int*)l, 16, 0, 0);
}

__global__ __launch_bounds__(256) void gemm_bf16x2(
    const unsigned short* __restrict__ ShC, const unsigned short* __restrict__ SlC,
    const unsigned short* __restrict__ Th, const unsigned short* __restrict__ Tl,
    unsigned short* __restrict__ Pb, const int* __restrict__ nmatch)
{
  int ay = blockIdx.x, bx = blockIdx.y;        // x = A tile (fast dim)
  if (ay * 128 >= *nmatch) return;

  __shared__ unsigned short lds[32768];        // Bh 32KB | Bl 32KB
  int tid = threadIdx.x, lane = tid & 63, wid = tid >> 6;

  const unsigned short* gB[2] = { Th + (size_t)bx * 128 * FD,
                                  Tl + (size_t)bx * 128 * FD };
  #pragma unroll
  for (int comp = 0; comp < 2; ++comp) {
    const char* g = (const char*)gB[comp];
    char* lb = (char*)lds + comp * 32768;
    #pragma unroll
    for (int it = 0; it < 8; ++it) {
      int chunk0 = it * 256 + wid * 64;
      int d = (chunk0 + lane) * 16;
      int src = d ^ (((d >> 8) & 7) << 4);
      gload16(g + src, lb + chunk0 * 16);
    }
  }

  int wr = wid >> 1, wc = wid & 1;             // 2x2 waves of 64x64
  const unsigned short* gA_h = ShC + (size_t)(ay * 128) * FD;
  const unsigned short* gA_l = SlC + (size_t)(ay * 128) * FD;
  int rA[4];
  #pragma unroll
  for (int m = 0; m < 4; ++m) rA[m] = wr * 64 + m * 16 + (lane & 15);
  int cA0 = (lane >> 4) * 8;

  s16x8 nah[4], nal[4];                        // kk=0 prefetch
  #pragma unroll
  for (int m = 0; m < 4; ++m) {
    nah[m] = *(const s16x8*)(gA_h + (size_t)rA[m] * FD + cA0);
    nal[m] = *(const s16x8*)(gA_l + (size_t)rA[m] * FD + cA0);
  }
  __syncthreads();

  f32x4 acc[4][4] = {};
  #pragma unroll
  for (int kk = 0; kk < 4; ++kk) {
    s16x8 ah[4], al[4];
    #pragma unroll
    for (int m = 0; m < 4; ++m) { ah[m] = nah[m]; al[m] = nal[m]; }
    if (kk < 3) {
      int cA = (kk + 1) * 32 + cA0;
      #pragma unroll
      for (int m = 0; m < 4; ++m) {
        nah[m] = *(const s16x8*)(gA_h + (size_t)rA[m] * FD + cA);
        nal[m] = *(const s16x8*)(gA_l + (size_t)rA[m] * FD + cA);
      }
    }
    int cB = kk * 32 + cA0;
    s16x8 bh[4], bl[4];
    #pragma unroll
    for (int n = 0; n < 4; ++n) {
      int r = wc * 64 + n * 16 + (lane & 15);
      int byt = r * 256 + ((cB * 2) ^ ((r & 7) << 4));
      bh[n] = *(const s16x8*)((const char*)lds + byt);
      bl[n] = *(const s16x8*)((const char*)lds + 32768 + byt);
    }
    #pragma unroll
    for (int m = 0; m < 4; ++m)
      #pragma unroll
      for (int n = 0; n < 4; ++n) {
        acc[m][n] = __builtin_amdgcn_mfma_f32_16x16x32_bf16(ah[m], bh[n], acc[m][n], 0, 0, 0);
        acc[m][n] = __builtin_amdgcn_mfma_f32_16x16x32_bf16(ah[m], bl[n], acc[m][n], 0, 0, 0);
        acc[m][n] = __builtin_amdgcn_mfma_f32_16x16x32_bf16(al[m], bh[n], acc[m][n], 0, 0, 0);
      }
  }

  // C/D layout: col = lane&15, row = (lane>>4)*4 + reg
  #pragma unroll
  for (int m = 0; m < 4; ++m)
    #pragma unroll
    for (int n = 0; n < 4; ++n) {
      int pc = bx * 128 + wc * 64 + n * 16 + (lane & 15);
      int pr0 = ay * 128 + wr * 64 + m * 16 + (lane >> 4) * 4;
      #pragma unroll
      for (int reg = 0; reg < 4; ++reg)
        Pb[(size_t)(pr0 + reg) * NT + pc] = f2bf(acc[m][n][reg] * TAUINV);
    }
}

// ---------------------------------------------------------------------------
// Exact top-k + logsumexp. Row staged in LDS (16 KB bf16), adaptive-range
// 512-bin histogram, shuffle suffix-scan, tie-exact candidate rank.
// Writes perrow[slot] with a PLAIN STORE -- r8-r10's fused finalize
// (per-block __threadfence + same-address global atomicAdd) was the ~270us
// floor across three different selection algorithms; reverted to r7's
// perrow + separate finalize kernel (64us proven).  pos stays fused (cheap).
// ---------------------------------------------------------------------------
__global__ __launch_bounds__(256) void select_lse(
    const unsigned short* __restrict__ Pb,
    const unsigned short* __restrict__ ShC, const unsigned short* __restrict__ SlC,
    const unsigned short* __restrict__ Th, const unsigned short* __restrict__ Tl,
    const int* __restrict__ mt, const int* __restrict__ nmatch,
    float* __restrict__ perrow)
{
  __shared__ __align__(16) unsigned short row[NT];   // 16 KB
  __shared__ unsigned hist[NBIN];                    // 2 KB
  __shared__ float cand[CAND_MAX];                   // 8 KB
  __shared__ float redMx[4], redMn[4], redF[4];
  __shared__ int redI[4];
  __shared__ unsigned wsum[4];
  __shared__ float sh_pos, sh_theta;
  __shared__ int sh_B, sh_j;
  __shared__ unsigned sh_cc;

  int tid = threadIdx.x, lane = tid & 63, wid = tid >> 6;
  int slot = blockIdx.x;
  if (slot >= *nmatch) return;

  const unsigned short* p = Pb + (size_t)slot * NT;

  // ---- wave 0: exact f32 positive dot (128 elems, 2/lane) ----
  if (wid == 0) {
    int t = mt[slot];
    int k0 = lane * 2;
    float a0 = bf2f(ShC[(size_t)slot * FD + k0])     + bf2f(SlC[(size_t)slot * FD + k0]);
    float a1 = bf2f(ShC[(size_t)slot * FD + k0 + 1]) + bf2f(SlC[(size_t)slot * FD + k0 + 1]);
    float b0 = bf2f(Th[(size_t)t * FD + k0])         + bf2f(Tl[(size_t)t * FD + k0]);
    float b1 = bf2f(Th[(size_t)t * FD + k0 + 1])     + bf2f(Tl[(size_t)t * FD + k0 + 1]);
    float sum = fmaf(a1, b1, a0 * b0);
    #pragma unroll
    for (int off = 32; off >= 1; off >>= 1) sum += __shfl_xor(sum, off, 64);
    if (lane == 0) sh_pos = sum * TAUINV;
  }

  // ---- load pass: global -> LDS row, track min/max ----
  float mx = -1e30f, mn = 1e30f;
  #pragma unroll
  for (int q = 0; q < 4; ++q) {
    s16x8 v = ((const s16x8*)p)[tid + 256 * q];
    ((s16x8*)row)[tid + 256 * q] = v;
    #pragma unroll
    for (int j = 0; j < 8; ++j) {
      float f = bf2f((unsigned short)v[j]);
      mx = fmaxf(mx, f);
      mn = fminf(mn, f);
    }
  }
  #pragma unroll
  for (int off = 32; off >= 1; off >>= 1) {
    mx = fmaxf(mx, __shfl_xor(mx, off, 64));
    mn = fminf(mn, __shfl_xor(mn, off, 64));
  }
  if (lane == 0) { redMx[wid] = mx; redMn[wid] = mn; }
  hist[tid] = 0; hist[tid + 256] = 0;
  if (tid == 0) sh_cc = 0;
  __syncthreads();                                           // B1

  float M  = fmaxf(fmaxf(redMx[0], redMx[1]), fmaxf(redMx[2], redMx[3]));
  float mn4 = fminf(fminf(redMn[0], redMn[1]), fminf(redMn[2], redMn[3]));
  float lo = mn4;
  float scale = (float)NBIN / fmaxf(M - mn4, 1e-9f);

  // ---- histogram pass (LDS row, adaptive bins) ----
  for (int i = tid; i < NT; i += 256) {
    float v = bf2f(row[i]);
    int bb = (int)((v - lo) * scale);
    bb = bb < 0 ? 0 : (bb > NBIN - 1 ? NBIN - 1 : bb);
    atomicAdd(&hist[bb], 1u);
  }
  __syncthreads();                                           // B2

  // ---- shuffle suffix-scan: thread t owns bins 2t, 2t+1 ----
  unsigned c0 = hist[2 * tid], c1 = hist[2 * tid + 1];
  unsigned s = c0 + c1;
  #pragma unroll
  for (int off = 1; off <= 32; off <<= 1) {
    unsigned t2 = __shfl_down(s, off, 64);
    if (lane + off < 64) s += t2;
  }
  if (lane == 0) wsum[wid] = s;     // s at lane 0 = wave's 128-bin total
  __syncthreads();                                           // B3
  unsigned add = 0;
  for (int w2 = wid + 1; w2 < 4; ++w2) add += wsum[w2];
  unsigned S0 = s + add;            // suffix sum from bin 2t
  unsigned S1 = S0 - c0;            // suffix sum from bin 2t+1
  if (c0 && S0 >= (unsigned)KTOP && S1 < (unsigned)KTOP) {
    sh_B = 2 * tid;  sh_j = KTOP - (int)S1;
  }
  unsigned S2 = S1 - c1;
  if (c1 && S1 >= (unsigned)KTOP && S2 < (unsigned)KTOP) {
    sh_B = 2 * tid + 1;  sh_j = KTOP - (int)S2;
  }
  __syncthreads();                                           // B4
  int B = sh_B;

  // ---- collect threshold-bin candidates ----
  for (int i = tid; i < NT; i += 256) {
    float v = bf2f(row[i]);
    int bb = (int)((v - lo) * scale);
    bb = bb < 0 ? 0 : (bb > NBIN - 1 ? NBIN - 1 : bb);
    if (bb == B) {
      unsigned idx = atomicAdd(&sh_cc, 1u);
      if (idx < CAND_MAX) cand[idx] = v;
    }
  }
  __syncthreads();                                           // B5
  int c = (int)sh_cc; if (c > CAND_MAX) c = CAND_MAX;
  int jrem = sh_j;   if (jrem > c) jrem = c;     // overflow/degenerate guard

  // ---- exact jrem-th largest among candidates (tie-exact) ----
  float thl = -1e30f;
  for (int i = tid; i < c; i += 256) {
    float v = cand[i];
    int gt = 0, eq = 0;
    for (int m = 0; m < c; ++m) {
      float u = cand[m];
      gt += (u > v) ? 1 : 0;
      eq += (u == v) ? 1 : 0;
    }
    if (gt < jrem && jrem <= gt + eq) thl = v;
  }
  #pragma unroll
  for (int off = 32; off >= 1; off >>= 1) thl = fmaxf(thl, __shfl_xor(thl, off, 64));
  if (lane == 0) redF[wid] = thl;
  __syncthreads();                                           // B6
  if (tid == 0) sh_theta = fmaxf(fmaxf(redF[0], redF[1]), fmaxf(redF[2], redF[3]));
  __syncthreads();                                           // B7

  float theta = sh_theta;
  float pos = sh_pos;
  float Mp = fmaxf(M, pos);

  // ---- exp-sum over strict top, tie copies via count ----
  float esum = 0.f; int g = 0;
  for (int i = tid; i < NT; i += 256) {
    float v = bf2f(row[i]);
    if (v > theta) { esum += __expf(v - Mp); g++; }
  }
  #pragma unroll
  for (int off = 32; off >= 1; off >>= 1) {
    esum += __shfl_xor(esum, off, 64);
    g    += __shfl_xor(g, off, 64);
  }
  if (lane == 0) { redF[wid] = esum; redI[wid] = g; }
  __syncthreads();                                           // B8
  if (tid == 0) {
    float E = redF[0] + redF[1] + redF[2] + redF[3];
    int   G = redI[0] + redI[1] + redI[2] + redI[3];
    float S = E + (float)(KTOP - G) * __expf(theta - Mp) + __expf(pos - Mp);
    perrow[slot] = logf(S) + Mp - pos;
  }
}

// ---------------------------------------------------------------------------
__global__ __launch_bounds__(256) void finalize(
    const float* __restrict__ perrow, const int* __restrict__ nmatch,
    float* __restrict__ out)
{
  __shared__ float ssum[4];
  int nm = *nmatch;
  float s = 0.f;
  for (int i = threadIdx.x; i < nm; i += 256) s += perrow[i];
  #pragma unroll
  for (int off = 32; off >= 1; off >>= 1) s += __shfl_xor(s, off, 64);
  int lane = threadIdx.x & 63, wid = threadIdx.x >> 6;
  if (lane == 0) ssum[wid] = s;
  __syncthreads();
  if (threadIdx.x == 0) {
    float S = ssum[0] + ssum[1] + ssum[2] + ssum[3];
    out[0] = S / fmaxf((float)nm, 1.f);
  }
}

// ---------------------------------------------------------------------------
extern "C" void kernel_launch(void* const* d_in, const int* in_sizes, int n_in,
                              void* d_out, int out_size, void* d_ws, size_t ws_size,
                              hipStream_t stream)
{
  const float* t_feat  = (const float*)d_in[0];
  const float* s_feat  = (const float*)d_in[1];
  const float* t_w1    = (const float*)d_in[2];
  const float* t_b1    = (const float*)d_in[3];
  const float* t_w2    = (const float*)d_in[4];
  const float* t_b2    = (const float*)d_in[5];
  const float* t_gamma = (const float*)d_in[6];
  const float* t_beta  = (const float*)d_in[7];
  const float* s_w1    = (const float*)d_in[8];
  const float* s_b1    = (const float*)d_in[9];
  const float* s_w2    = (const float*)d_in[10];
  const float* s_b2    = (const float*)d_in[11];
  const float* s_gamma = (const float*)d_in[12];
  const float* s_beta  = (const float*)d_in[13];
  const int*   t_coord = (const int*)d_in[14];
  const int*   s_coord = (const int*)d_in[15];

  // ws layout (bytes), ws_size = 256 MiB:
  //  0x000000 Th 2MB | 0x200000 Tl 2MB | 0x400000 ShC 2MB | 0x600000 SlC 2MB
  //  0x800000 stats 2KB | 0x800800 hkey 256KB | 0x840800 hval 256KB
  //  0x880800 nmatch | 0x880900 mt 32KB | 0x888900 minv 32KB
  //  0x890900 perrow 32KB
  //  0x8B0000 Ht 4MB, Hs 4MB (dead after bn) -- Pb bf16 (64MB) aliases here
  char* w = (char*)d_ws;
  unsigned short* Th  = (unsigned short*)(w + 0x000000);
  unsigned short* Tl  = (unsigned short*)(w + 0x200000);
  unsigned short* ShC = (unsigned short*)(w + 0x400000);
  unsigned short* SlC = (unsigned short*)(w + 0x600000);
  float* stats  = (float*)(w + 0x800000);
  int*   hkey   = (int*)(w + 0x800800);
  int*   hval   = (int*)(w + 0x840800);
  int*   nmatch = (int*)(w + 0x880800);
  int*   mt     = (int*)(w + 0x880900);
  int*   minv   = (int*)(w + 0x888900);
  float* perrow = (float*)(w + 0x890900);
  float* Ht     = (float*)(w + 0x8B0000);
  float* Hs     = (float*)(w + 0xCB0000);
  unsigned short* Pb = (unsigned short*)(w + 0x8B0000);  // aliases Ht/Hs

  init_ws<<<HSIZE / 256, 256, 0, stream>>>(stats, hkey, nmatch);
  hash_insert<<<NT / 256, 256, 0, stream>>>(t_coord, hkey, hval);
  hash_lookup<<<NS / 256, 256, 0, stream>>>(s_coord, hkey, hval, minv, mt, nmatch);

  {
    dim3 g(NT / 32, 2);
    proj_mlp2<<<g, 256, 0, stream>>>(t_feat, s_feat,
                                     t_w1, t_b1, t_w2, t_b2,
                                     s_w1, s_b1, s_w2, s_b2,
                                     Ht, Hs, stats);
  }
  {
    dim3 g(NT / 2, 2);
    bn_l2_2<<<g, 256, 0, stream>>>(Ht, Hs, stats, t_gamma, t_beta,
                                   s_gamma, s_beta, Th, Tl, ShC, SlC, minv);
  }
  {
    dim3 g(NMC / 128, NT / 128);             // x = A tiles (fast), y = B tiles
    gemm_bf16x2<<<g, 256, 0, stream>>>(ShC, SlC, Th, Tl, Pb, nmatch);
  }
  select_lse<<<NMC, 256, 0, stream>>>(Pb, ShC, SlC, Th, Tl, mt, nmatch, perrow);
  finalize<<<1, 256, 0, stream>>>(perrow, nmatch, (float*)d_out);
}